// Round 1
// baseline (450.936 us; speedup 1.0000x reference)
//
#include <hip/hip_runtime.h>
#include <hip/hip_bf16.h>

// MultiHeadAttention: B=4, S=2048, D=1024, H=16, Dh=64. I/O fp32, compute bf16.
// R7: flash_attn latency fixes:
//   (a) prefetch-split K/V staging: issue next-tile global loads AFTER the
//       staging barriers so compute covers the latency (__syncthreads drains
//       vmcnt(0), so loads issued right before a barrier get zero overlap);
//   (b) XCD-chunked block swizzle: 8 heads per XCD -> K/V working set 4MB = L2;
//   (c) s_setprio(1) around MFMA clusters.
// GEMMs unchanged (dispatch order already partitions m-tiles per XCD).

typedef __bf16 bf16_t;
typedef __attribute__((ext_vector_type(8))) __bf16 bf16x8;
typedef __attribute__((ext_vector_type(4))) __bf16 bf16x4;
typedef __attribute__((ext_vector_type(4))) float f32x4;

#define MFMA(a, b, c) __builtin_amdgcn_mfma_f32_16x16x32_bf16((a), (b), (c), 0, 0, 0)

__device__ __forceinline__ float fast_exp2(float x) {
#if __has_builtin(__builtin_amdgcn_exp2f)
  return __builtin_amdgcn_exp2f(x);
#else
  return exp2f(x);
#endif
}

__device__ __forceinline__ bf16x8 load8_bf16(const bf16_t* p) {
  return *(const bf16x8*)p;
}
__device__ __forceinline__ bf16x8 load8_bf16(const float* p) {
  f32x4 a = *(const f32x4*)p;
  f32x4 b = *(const f32x4*)(p + 4);
  bf16x8 r;
  for (int i = 0; i < 4; ++i) { r[i] = (bf16_t)a[i]; r[i + 4] = (bf16_t)b[i]; }
  return r;
}

__device__ __forceinline__ void gload_lds16(const bf16_t* g, bf16_t* l) {
  __builtin_amdgcn_global_load_lds(
      (const __attribute__((address_space(1))) void*)g,
      (__attribute__((address_space(3))) void*)l, 16, 0, 0);
}

// ---------------- fp32 -> bf16 bulk convert ----------------
__global__ __launch_bounds__(256) void convert_bf16(
    const float* __restrict__ xq, const float* __restrict__ xk, const float* __restrict__ xv,
    const float* __restrict__ wq, const float* __restrict__ wk, const float* __restrict__ wv,
    const float* __restrict__ wo,
    bf16_t* __restrict__ xqb, bf16_t* __restrict__ xkb, bf16_t* __restrict__ xvb,
    bf16_t* __restrict__ wqb, bf16_t* __restrict__ wkb, bf16_t* __restrict__ wvb,
    bf16_t* __restrict__ wob) {
  const float* s;
  bf16_t* d;
  size_t n;
  switch (blockIdx.y) {
    case 0: s = xq; d = xqb; n = 8388608; break;
    case 1: s = xk; d = xkb; n = 8388608; break;
    case 2: s = xv; d = xvb; n = 8388608; break;
    case 3: s = wq; d = wqb; n = 1048576; break;
    case 4: s = wk; d = wkb; n = 1048576; break;
    case 5: s = wv; d = wvb; n = 1048576; break;
    default: s = wo; d = wob; n = 1048576; break;
  }
  size_t idx = ((size_t)blockIdx.x * 256 + threadIdx.x) * 8;
  if (idx < n) *(bf16x8*)&d[idx] = load8_bf16(&s[idx]);
}

// ---------------- GEMM: C[m,n] = (sum_k A[m,k]*W[n,k] + bias[n]) * sc --------
// M = grid.x*128, N = grid.y*128, K = 1024. Row-major, K contiguous (NT gemm).
// ASYNC: global_load_lds staging (requires TA=TW=bf16).
// VT: write per-head transposed Vt[((b*16+h)*64+d)*2048+s]. QS: scale output.
template <typename TA, typename TW, typename TC, bool VT, bool QS, bool ASYNC>
__device__ __forceinline__ void gemm_body(const TA* __restrict__ A,
                                          const TW* __restrict__ W,
                                          const float* __restrict__ bia,
                                          TC* __restrict__ C) {
  __shared__ __align__(16) bf16_t sA[128 * 32];
  __shared__ __align__(16) bf16_t sW[128 * 32];
  const int tid = threadIdx.x;
  const int lane = tid & 63;
  const int w = tid >> 6;
  const int ln = lane & 15;
  const int q = lane >> 4;
  const int wm = w >> 1, wn = w & 1;
  const size_t m0 = (size_t)blockIdx.x * 128;
  const size_t n0 = (size_t)blockIdx.y * 128;
  const int r0 = tid >> 2;          // sync-staging row (chunk = tid)
  const int ko = (tid & 3) * 8;

  f32x4 zero = {0.f, 0.f, 0.f, 0.f};
  f32x4 acc[4][4];
  for (int i = 0; i < 4; ++i)
    for (int j = 0; j < 4; ++j) acc[i][j] = zero;

  for (int k0 = 0; k0 < 1024; k0 += 32) {
    if (ASYNC) {
      __syncthreads();  // previous iteration's LDS readers done
      for (int i = 0; i < 2; ++i) {
        int c = w * 64 + i * 256 + lane;   // chunk 0..511
        int row = c >> 2;
        int k2 = (c & 3) * 8;
        gload_lds16((const bf16_t*)A + (m0 + row) * 1024 + k0 + k2,
                    &sA[(w * 64 + i * 256) * 8]);
        gload_lds16((const bf16_t*)W + (n0 + row) * 1024 + k0 + k2,
                    &sW[(w * 64 + i * 256) * 8]);
      }
      __syncthreads();  // vmcnt(0) drain before barrier completes staging
    } else {
      bf16x8 a0 = load8_bf16(&A[(m0 + r0) * 1024 + k0 + ko]);
      bf16x8 a1 = load8_bf16(&A[(m0 + 64 + r0) * 1024 + k0 + ko]);
      bf16x8 w0 = load8_bf16(&W[(n0 + r0) * 1024 + k0 + ko]);
      bf16x8 w1 = load8_bf16(&W[(n0 + 64 + r0) * 1024 + k0 + ko]);
      __syncthreads();
      *(bf16x8*)&sA[tid * 8] = a0;
      *(bf16x8*)&sA[(tid + 256) * 8] = a1;
      *(bf16x8*)&sW[tid * 8] = w0;
      *(bf16x8*)&sW[(tid + 256) * 8] = w1;
      __syncthreads();
    }

    bf16x8 af[4], bfr[4];
    for (int t = 0; t < 4; ++t)
      af[t] = *(const bf16x8*)&sA[(wm * 64 + t * 16 + ln) * 32 + q * 8];
    for (int t = 0; t < 4; ++t)
      bfr[t] = *(const bf16x8*)&sW[(wn * 64 + t * 16 + ln) * 32 + q * 8];
    for (int tm = 0; tm < 4; ++tm)
      for (int tn = 0; tn < 4; ++tn)
        acc[tm][tn] = MFMA(af[tm], bfr[tn], acc[tm][tn]);
  }

  const float sc = QS ? 0.180336880f : 1.0f;  // 0.125 * log2(e)
  for (int tn = 0; tn < 4; ++tn) {
    size_t gc = n0 + wn * 64 + tn * 16 + ln;
    float bv = bia[gc];
    for (int tm = 0; tm < 4; ++tm) {
      size_t gr0 = m0 + wm * 64 + tm * 16 + q * 4;
      if (VT) {
        size_t bidx = gr0 >> 11, s0 = gr0 & 2047;
        size_t h = gc >> 6, d = gc & 63;
        bf16x4 pk;
        for (int r = 0; r < 4; ++r) pk[r] = (bf16_t)(acc[tm][tn][r] + bv);
        *(bf16x4*)&((bf16_t*)C)[((bidx * 16 + h) * 64 + d) * 2048 + s0] = pk;
      } else {
        for (int r = 0; r < 4; ++r) {
          float v = (acc[tm][tn][r] + bv) * sc;
          C[(gr0 + r) * 1024 + gc] = (TC)v;
        }
      }
    }
  }
}

// bf16 fast path (ASYNC staging)
__global__ __launch_bounds__(256) void gemm_qkv_b(
    const bf16_t* __restrict__ Xq, const bf16_t* __restrict__ Xk, const bf16_t* __restrict__ Xv,
    const bf16_t* __restrict__ Wq, const bf16_t* __restrict__ Wk, const bf16_t* __restrict__ Wv,
    const float* __restrict__ Bq, const float* __restrict__ Bk, const float* __restrict__ Bv,
    bf16_t* __restrict__ Oq, bf16_t* __restrict__ Ok, bf16_t* __restrict__ Ov) {
  if (blockIdx.z == 0)      gemm_body<bf16_t, bf16_t, bf16_t, false, true , true>(Xq, Wq, Bq, Oq);
  else if (blockIdx.z == 1) gemm_body<bf16_t, bf16_t, bf16_t, false, false, true>(Xk, Wk, Bk, Ok);
  else                      gemm_body<bf16_t, bf16_t, bf16_t, true , false, true>(Xv, Wv, Bv, Ov);
}
__global__ __launch_bounds__(256) void gemm_out_b(
    const bf16_t* __restrict__ A, const bf16_t* __restrict__ W,
    const float* __restrict__ bia, float* __restrict__ C) {
  gemm_body<bf16_t, bf16_t, float, false, false, true>(A, W, bia, C);
}

// fp32-input fallback (register staging + fused convert)
__global__ __launch_bounds__(256) void gemm_qkv_f(
    const float* __restrict__ Xq, const float* __restrict__ Xk, const float* __restrict__ Xv,
    const float* __restrict__ Wq, const float* __restrict__ Wk, const float* __restrict__ Wv,
    const float* __restrict__ Bq, const float* __restrict__ Bk, const float* __restrict__ Bv,
    bf16_t* __restrict__ Oq, bf16_t* __restrict__ Ok, bf16_t* __restrict__ Ov) {
  if (blockIdx.z == 0)      gemm_body<float, float, bf16_t, false, true , false>(Xq, Wq, Bq, Oq);
  else if (blockIdx.z == 1) gemm_body<float, float, bf16_t, false, false, false>(Xk, Wk, Bk, Ok);
  else                      gemm_body<float, float, bf16_t, true , false, false>(Xv, Wv, Bv, Ov);
}
__global__ __launch_bounds__(256) void gemm_out_f(
    const bf16_t* __restrict__ A, const float* __restrict__ W,
    const float* __restrict__ bia, float* __restrict__ C) {
  gemm_body<bf16_t, float, float, false, false, false>(A, W, bia, C);
}

// ---------------- Flash attention (unnormalized exp2 softmax) ----------------
// Q pre-scaled by 0.125*log2e; K in [B*S,1024]; Vt in [b][h][64][2048].
// 512 threads (8 waves); BR=128 q-rows (wave w owns rows w*16..w*16+15),
// BC=64 keys/iter. grid = (S/128, B*H). LDS stride 68 everywhere.
// R7: XCD-chunked swizzle + prefetch-split staging + setprio.
__global__ __launch_bounds__(512, 8) void flash_attn(const bf16_t* __restrict__ Q,
                                                     const bf16_t* __restrict__ K,
                                                     const bf16_t* __restrict__ Vt,
                                                     bf16_t* __restrict__ O) {
  __shared__ __align__(16) bf16_t sQP[128 * 68];  // Q tile; reused as P strips
  __shared__ __align__(16) bf16_t sK[64 * 68];    // [key][d]
  __shared__ __align__(16) bf16_t sVt[64 * 68];   // [d][key]

  const int tid = threadIdx.x;
  const int lane = tid & 63;
  const int w = tid >> 6;          // 0..7
  const int ln = lane & 15;
  const int q = lane >> 4;

  // XCD-chunked bijective swizzle (nwg=1024, 8 XCDs, chunk=128):
  // dispatch d -> XCD d%8 (empirical round-robin). Default mapping gives each
  // XCD all 64 heads (K/V working set 32MB >> 4MB L2). Chunked mapping gives
  // each XCD 8 consecutive heads x all 16 q-tiles -> working set 4MB = L2.
  const int id = (int)blockIdx.x + 16 * (int)blockIdx.y;
  const int id2 = (id & 7) * 128 + (id >> 3);
  const int bh = id2 >> 4;
  const int q0 = (id2 & 15) * 128;
  const int b = bh >> 4;
  const int h = bh & 15;

  const bf16_t* Qb = Q + ((size_t)b * 2048 + q0) * 1024 + h * 64;
  const bf16_t* Kb = K + ((size_t)b * 2048) * 1024 + h * 64;
  const bf16_t* VtB = Vt + (size_t)bh * 64 * 2048;

  const int krow = tid >> 3;           // 0..63 (512 thr = 64 rows x 8 chunks)
  const int koff = (tid & 7) * 8;

  // prologue prefetch of tile 0 (covered by Q staging + barrier)
  bf16x8 kreg = *(const bf16x8*)&Kb[(size_t)krow * 1024 + koff];
  bf16x8 vreg = *(const bf16x8*)&VtB[(size_t)krow * 2048 + koff];

  // stage Q tile [128][64]
  for (int i = 0; i < 2; ++i) {
    int c = tid + 512 * i;        // 0..1023
    int row = c >> 3;             // 0..127
    int off = (c & 7) * 8;
    *(bf16x8*)&sQP[row * 68 + off] = *(const bf16x8*)&Qb[(size_t)row * 1024 + off];
  }
  __syncthreads();
  bf16x8 qf[2];
  qf[0] = *(const bf16x8*)&sQP[(w * 16 + ln) * 68 + q * 8];
  qf[1] = *(const bf16x8*)&sQP[(w * 16 + ln) * 68 + 32 + q * 8];
  bf16_t* sP = &sQP[w * 16 * 68];  // wave-private strip [16][68]

  f32x4 zero = {0.f, 0.f, 0.f, 0.f};
  f32x4 oacc[4];
  for (int t = 0; t < 4; ++t) oacc[t] = zero;
  float lpart[4] = {0.f, 0.f, 0.f, 0.f};

  for (int j0 = 0; j0 < 2048; j0 += 64) {
    __syncthreads();  // prev readers done; also drains prefetched vmcnt
    *(bf16x8*)&sK[krow * 68 + koff] = kreg;
    *(bf16x8*)&sVt[krow * 68 + koff] = vreg;
    __syncthreads();

    // prefetch NEXT K/V tile now: the whole QK^T+exp2+PV phase hides the
    // global latency; the drain happens at next iteration's first barrier.
    if (j0 + 64 < 2048) {
      kreg = *(const bf16x8*)&Kb[(size_t)(j0 + 64 + krow) * 1024 + koff];
      vreg = *(const bf16x8*)&VtB[(size_t)krow * 2048 + (j0 + 64) + koff];
    }

    // S' = Qs K^T (strip [16 x 64]), already in exp2 domain
    f32x4 sacc[4];
    for (int t = 0; t < 4; ++t) sacc[t] = zero;
    __builtin_amdgcn_s_setprio(1);
    for (int kk = 0; kk < 2; ++kk)
      for (int tn = 0; tn < 4; ++tn) {
        bf16x8 kf = *(const bf16x8*)&sK[(tn * 16 + ln) * 68 + kk * 32 + q * 8];
        sacc[tn] = MFMA(qf[kk], kf, sacc[tn]);
      }
    __builtin_amdgcn_s_setprio(0);

    // P = exp2(S'); per-lane row partials; stash P (A-layout transform via LDS)
    for (int tn = 0; tn < 4; ++tn)
      for (int r = 0; r < 4; ++r) {
        float p = fast_exp2(sacc[tn][r]);
        lpart[r] += p;
        sP[(q * 4 + r) * 68 + tn * 16 + ln] = (bf16_t)p;
      }

    // O += P V
    __builtin_amdgcn_s_setprio(1);
    for (int kk = 0; kk < 2; ++kk) {
      bf16x8 pf = *(const bf16x8*)&sP[ln * 68 + kk * 32 + q * 8];
      for (int tn = 0; tn < 4; ++tn) {
        bf16x8 vf = *(const bf16x8*)&sVt[(tn * 16 + ln) * 68 + kk * 32 + q * 8];
        oacc[tn] = MFMA(pf, vf, oacc[tn]);
      }
    }
    __builtin_amdgcn_s_setprio(0);
  }

  for (int m = 1; m < 16; m <<= 1)
    for (int r = 0; r < 4; ++r) lpart[r] += __shfl_xor(lpart[r], m);

  bf16_t* Ob = O + ((size_t)b * 2048 + q0 + w * 16) * 1024 + h * 64;
  for (int r = 0; r < 4; ++r) {
    float inv = 1.f / lpart[r];
    for (int tn = 0; tn < 4; ++tn)
      Ob[(size_t)(q * 4 + r) * 1024 + tn * 16 + ln] = (bf16_t)(oacc[tn][r] * inv);
  }
}

// ---------------- launch ----------------
extern "C" void kernel_launch(void* const* d_in, const int* in_sizes, int n_in,
                              void* d_out, int out_size, void* d_ws, size_t ws_size,
                              hipStream_t stream) {
  (void)in_sizes; (void)n_in; (void)out_size;
  const float* query = (const float*)d_in[0];
  const float* key   = (const float*)d_in[1];
  const float* value = (const float*)d_in[2];
  const float* Wq = (const float*)d_in[3];
  const float* bq = (const float*)d_in[4];
  const float* Wk = (const float*)d_in[5];
  const float* bk = (const float*)d_in[6];
  const float* Wv = (const float*)d_in[7];
  const float* bv = (const float*)d_in[8];
  const float* Wo = (const float*)d_in[9];
  const float* bo = (const float*)d_in[10];
  float* out = (float*)d_out;

  const size_t MD = (size_t)8192 * 1024;   // X elements
  const size_t WD = (size_t)1024 * 1024;   // W elements
  bf16_t* base = (bf16_t*)d_ws;
  bf16_t* Qw  = base;
  bf16_t* Kw  = Qw + MD;
  bf16_t* Vtw = Kw + MD;   // [b][h][64][2048]

  dim3 b256(256), b512(512);
  if (ws_size >= (6 * MD + 4 * WD) * sizeof(bf16_t)) {
    // fast path: pre-convert to bf16, m97 async-staged GEMMs
    bf16_t* XqB = Vtw + MD;  // also reused as AO after gemm_qkv
    bf16_t* XkB = XqB + MD;
    bf16_t* XvB = XkB + MD;
    bf16_t* WqB = XvB + MD;
    bf16_t* WkB = WqB + WD;
    bf16_t* WvB = WkB + WD;
    bf16_t* WoB = WvB + WD;
    bf16_t* AO  = XqB;       // alias: XqB dead after gemm_qkv

    convert_bf16<<<dim3(4096, 7), b256, 0, stream>>>(
        query, key, value, Wq, Wk, Wv, Wo,
        XqB, XkB, XvB, WqB, WkB, WvB, WoB);
    gemm_qkv_b<<<dim3(64, 8, 3), b256, 0, stream>>>(
        XqB, XkB, XvB, WqB, WkB, WvB, bq, bk, bv, Qw, Kw, Vtw);
    flash_attn<<<dim3(16, 64), b512, 0, stream>>>(Qw, Kw, Vtw, AO);
    gemm_out_b<<<dim3(64, 8), b256, 0, stream>>>(AO, WoB, bo, out);
  } else {
    // fallback: fused-convert GEMMs (needs 64 MB ws)
    bf16_t* AO = Vtw + MD;
    gemm_qkv_f<<<dim3(64, 8, 3), b256, 0, stream>>>(
        query, key, value, Wq, Wk, Wv, bq, bk, bv, Qw, Kw, Vtw);
    flash_attn<<<dim3(16, 64), b512, 0, stream>>>(Qw, Kw, Vtw, AO);
    gemm_out_f<<<dim3(64, 8), b256, 0, stream>>>(AO, Wo, bo, out);
  }
}